// Round 13
// baseline (524.342 us; speedup 1.0000x reference)
//
#include <hip/hip_runtime.h>
#include <math.h>

#define NU_    100000
#define NI_    50000
#define NB_    20000
#define DIM    64
#define E_UI_  2000000
#define E_BI_  600000
#define NPROP  (2 * E_UI_)
#define NTOT   (NU_ + NI_)
#define BATCH  4096
#define NBIN_P ((NTOT + 255) / 256)   // 586
#define NBIN_B ((NB_  + 255) / 256)   // 79

// Private-cell multisplit geometry: binned[bin][block][slot].
// P: lambda = 4M/(512*586) = 10.2 per cell; SLICE_P=40 is +~9 sigma.
// B: lambda = 600K/(96*79) = 79 per cell; SLICE_B=160 is +~9 sigma.
#define VG_P     512
#define SLICE_P  40
#define BINSZ_P  (VG_P * SLICE_P)     // 20480 slots per P bin
#define VG_B     96
#define SLICE_B  160
#define BINSZ_B  (VG_B * SLICE_B)     // 15360 slots per B bin
#define EBUF_CAP 12288                // max valid entries per bin (~10.4K item bins)

#define MS_TOTAL    (VG_B + VG_P)     // 608 multisplit blocks (co-resident)
#define CAST_BLOCKS ((NTOT * 16) / 256)   // 9375 (exact)
#define SCORE_BLOCKS (BATCH / 4)          // 1024, one wave per sample

// ---------------------------------------------------------------------------
// bf16 helpers
__device__ __forceinline__ float bflo(unsigned int u) {
    return __uint_as_float(u << 16);
}
__device__ __forceinline__ float bfhi(unsigned int u) {
    return __uint_as_float(u & 0xFFFF0000u);
}
__device__ __forceinline__ unsigned short f2bf(float f) {         // RNE
    unsigned int u = __float_as_uint(f);
    u += 0x7FFFu + ((u >> 16) & 1u);
    return (unsigned short)(u >> 16);
}
__device__ __forceinline__ unsigned int pack2(float a, float b) {
    return (unsigned int)f2bf(a) | ((unsigned int)f2bf(b) << 16);
}

// ---------------------------------------------------------------------------
// Fused multisplit (private cells, ZERO global atomics) + bf16 cast.
// Block order: [B: 0..96) [P: 96..608) [cast: 608..9983).
// payload = ((row & 255) << 24) | col
__global__ void mscast_kernel(const int* __restrict__ prows,
                              const int* __restrict__ pcols,
                              const int* __restrict__ brows,
                              const int* __restrict__ bcols,
                              unsigned int* __restrict__ binnedP,
                              int* __restrict__ cellcntP,
                              unsigned int* __restrict__ binnedB,
                              int* __restrict__ cellcntB,
                              const float4* __restrict__ uf4,
                              const float4* __restrict__ itf4,
                              uint2* __restrict__ feats_out) {
    constexpr int BUF = 16;
    __shared__ int cnt[NBIN_P];                 // staged-but-unflushed count
    __shared__ int fpos[NBIN_P];                // flushed count (cell-relative)
    __shared__ int basep[NBIN_P];               // flush base for current phase
    __shared__ unsigned int stage[NBIN_P][BUF];
    int bid = blockIdx.x;
    if (bid >= MS_TOTAL) {
        // ---- cast lane ----
        int i = (bid - MS_TOTAL) * 256 + threadIdx.x;
        const int nuq = NU_ * 16;
        const int totq = NTOT * 16;
        if (i < totq) {
            float4 v = (i < nuq) ? uf4[i] : itf4[i - nuq];
            uint2 o;
            o.x = pack2(v.x, v.y);
            o.y = pack2(v.z, v.w);
            feats_out[i] = o;
        }
        return;
    }
    const int *rows, *cols; int n, nbin, vb, vgrid, slice; size_t binsz;
    unsigned int* binned; int* cellcnt;
    if (bid < VG_B) {
        rows = brows; cols = bcols; n = E_BI_; nbin = NBIN_B;
        vb = bid; vgrid = VG_B; slice = SLICE_B; binsz = BINSZ_B;
        binned = binnedB; cellcnt = cellcntB;
    } else {
        rows = prows; cols = pcols; n = NPROP; nbin = NBIN_P;
        vb = bid - VG_B; vgrid = VG_P; slice = SLICE_P; binsz = BINSZ_P;
        binned = binnedP; cellcnt = cellcntP;
    }
    for (int i = threadIdx.x; i < nbin; i += 256) { cnt[i] = 0; fpos[i] = 0; }
    __syncthreads();
    int stride = vgrid * 1024;
    for (int base = vb * 1024; base < n; base += stride) {
        int bin[4], pos[4];
        unsigned int payload[4];
        #pragma unroll
        for (int j = 0; j < 4; ++j) {
            int i = base + j * 256 + threadIdx.x;   // coalesced per step
            pos[j] = -1;
            if (i < n) {
                int r = rows[i];
                int c = cols[i];
                bin[j] = r >> 8;
                payload[j] = ((unsigned int)(r & 255) << 24) | (unsigned int)c;
                pos[j] = atomicAdd(&cnt[bin[j]], 1);
                if (pos[j] < BUF) stage[bin[j]][pos[j]] = payload[j];
            }
        }
        __syncthreads();
        #pragma unroll
        for (int j = 0; j < 4; ++j)
            if (pos[j] == BUF) {               // unique leader per bin per phase
                basep[bin[j]] = fpos[bin[j]];
                fpos[bin[j]] += cnt[bin[j]];
            }
        __syncthreads();
        #pragma unroll
        for (int j = 0; j < 4; ++j) {
            if (pos[j] >= BUF) {
                size_t cb = (size_t)bin[j] * binsz + (size_t)vb * slice;
                int rel = basep[bin[j]] + pos[j];
                if (rel < slice) binned[cb + rel] = payload[j];
                if (pos[j] == BUF) {
                    int b0 = basep[bin[j]];
                    #pragma unroll
                    for (int q = 0; q < BUF; ++q)
                        if (b0 + q < slice) binned[cb + b0 + q] = stage[bin[j]][q];
                    cnt[bin[j]] = 0;
                }
            }
        }
        __syncthreads();
    }
    // drain residual staged entries + write exact cell counts
    for (int b = threadIdx.x; b < nbin; b += 256) {
        int c = cnt[b];
        int f = fpos[b];
        size_t cb = (size_t)b * binsz + (size_t)vb * slice;
        for (int j = 0; j < c && f + j < slice; ++j) binned[cb + f + j] = stage[b][j];
        int tot = f + c;
        if (tot > slice) tot = slice;
        cellcnt[b * vgrid + vb] = tot;
    }
}

// ---------------------------------------------------------------------------
// Per-bin CSR build (P: blocks [0,586), B: [586,665)). Gathers the bin's
// private cells into LDS (via cell counts), then hist/scan/place; compacted
// cv is rewritten IN PLACE into the bin's own region (all reads precede writes).
__global__ void bin_csr_kernel(unsigned int* __restrict__ binnedP,
                               const int* __restrict__ cellcntP,
                               int* __restrict__ offP, int* __restrict__ degP,
                               float* __restrict__ invsP,
                               unsigned int* __restrict__ binnedB,
                               const int* __restrict__ cellcntB,
                               int* __restrict__ offB, int* __restrict__ degB) {
    __shared__ unsigned int ebuf[EBUF_CAP];    // 48 KB
    __shared__ int ccnt[VG_P];                 // 512
    __shared__ int cstart[VG_P];
    __shared__ int s2[256];
    __shared__ int cnt[256];
    __shared__ int cur[256];
    __shared__ int scanbuf[256];
    unsigned int* binned; const int* cellcnt;
    int* off; int* deg; float* invs;
    int b, nrows, vgrid, slice; size_t binsz;
    if (blockIdx.x < NBIN_P) {
        b = blockIdx.x; binned = binnedP; cellcnt = cellcntP; nrows = NTOT;
        vgrid = VG_P; slice = SLICE_P; binsz = BINSZ_P;
        off = offP; deg = degP; invs = invsP;
    } else {
        b = blockIdx.x - NBIN_P; binned = binnedB; cellcnt = cellcntB; nrows = NB_;
        vgrid = VG_B; slice = SLICE_B; binsz = BINSZ_B;
        off = offB; deg = degB; invs = (float*)0;
    }
    int t = threadIdx.x;
    int rowbase = b << 8;
    // load per-cell counts
    for (int i = t; i < vgrid; i += 256) ccnt[i] = cellcnt[b * vgrid + i];
    __syncthreads();
    // exclusive scan of ccnt (vgrid <= 512) via pair-sum + 256-scan
    int a0 = (2 * t     < vgrid) ? ccnt[2 * t]     : 0;
    int a1 = (2 * t + 1 < vgrid) ? ccnt[2 * t + 1] : 0;
    s2[t] = a0 + a1;
    __syncthreads();
    for (int o = 1; o < 256; o <<= 1) {
        int y = (t >= o) ? s2[t - o] : 0;
        __syncthreads();
        s2[t] += y;
        __syncthreads();
    }
    int e2 = s2[t] - (a0 + a1);   // exclusive
    if (2 * t     < vgrid) cstart[2 * t]     = e2;
    if (2 * t + 1 < vgrid) cstart[2 * t + 1] = e2 + a0;
    cnt[t] = 0;
    __syncthreads();
    int m = s2[255];              // total valid entries in bin
    if (m > EBUF_CAP) m = EBUF_CAP;
    // gather cells into ebuf: wave per cell
    int wv = t >> 6, ln = t & 63;
    size_t gbase = (size_t)b * binsz;
    for (int c = wv; c < vgrid; c += 4) {
        int k = ccnt[c];
        int st = cstart[c];
        size_t gb = gbase + (size_t)c * slice;
        for (int i = ln; i < k; i += 64)
            if (st + i < EBUF_CAP) ebuf[st + i] = binned[gb + i];
    }
    __syncthreads();
    // per-row histogram
    for (int i = t; i < m; i += 256)
        atomicAdd(&cnt[ebuf[i] >> 24], 1);
    __syncthreads();
    int x = cnt[t];
    scanbuf[t] = x;
    __syncthreads();
    for (int o = 1; o < 256; o <<= 1) {
        int y = (t >= o) ? scanbuf[t - o] : 0;
        __syncthreads();
        scanbuf[t] += y;
        __syncthreads();
    }
    int base = scanbuf[t] - x;    // bin-local compact offset
    cur[t] = base;
    if (rowbase + t < nrows) {
        off[rowbase + t] = (int)gbase + base;
        deg[rowbase + t] = x;
        if (invs) invs[rowbase + t] = 1.0f / (sqrtf((float)x) + 1e-8f);
    }
    __syncthreads();
    // in-place compacted cv fill from LDS copy
    for (int i = t; i < m; i += 256) {
        unsigned int p = ebuf[i];
        int slot = atomicAdd(&cur[p >> 24], 1);
        binned[gbase + slot] = p & 0xFFFFFFu;
    }
}

// ---------------------------------------------------------------------------
// 8 lanes/row, uint4 = 8 bf16 per lane. 8 rows/wave, 32 rows per 256-block.
__device__ __forceinline__ void fma8(float* s, float v, uint4 x) {
    s[0] = fmaf(v, bflo(x.x), s[0]);
    s[1] = fmaf(v, bfhi(x.x), s[1]);
    s[2] = fmaf(v, bflo(x.y), s[2]);
    s[3] = fmaf(v, bfhi(x.y), s[3]);
    s[4] = fmaf(v, bflo(x.z), s[4]);
    s[5] = fmaf(v, bfhi(x.z), s[5]);
    s[6] = fmaf(v, bflo(x.w), s[6]);
    s[7] = fmaf(v, bfhi(x.w), s[7]);
}
__device__ __forceinline__ uint4 pack8(const float* s) {
    uint4 o;
    o.x = pack2(s[0], s[1]);
    o.y = pack2(s[2], s[3]);
    o.z = pack2(s[4], s[5]);
    o.w = pack2(s[6], s[7]);
    return o;
}

// Layer 1: sum = Σ invs[c]·feats[c]; acc16[r] = feats[r] + invs[r]·sum;
//          f1s16[r] = invs[r]²·sum
__global__ void layer1_kernel(const int* __restrict__ off,
                              const int* __restrict__ deg,
                              const unsigned int* __restrict__ cv,
                              const float* __restrict__ invs,
                              const uint4* __restrict__ feats16,
                              uint4* __restrict__ f1s16,
                              uint4* __restrict__ acc16) {
    int wave = blockIdx.x * (blockDim.x >> 6) + (threadIdx.x >> 6);
    int sub  = (threadIdx.x >> 3) & 7;
    int l    = threadIdx.x & 7;
    int row  = wave * 8 + sub;
    if (row >= NTOT) return;
    int s = off[row], d = deg[row];
    float sum[8] = {0.f, 0.f, 0.f, 0.f, 0.f, 0.f, 0.f, 0.f};
    int k = 0;
    for (; k + 4 <= d; k += 4) {
        int c0 = (int)cv[s + k + 0];
        int c1 = (int)cv[s + k + 1];
        int c2 = (int)cv[s + k + 2];
        int c3 = (int)cv[s + k + 3];
        float w0 = invs[c0], w1 = invs[c1], w2 = invs[c2], w3 = invs[c3];
        uint4 x0 = feats16[(size_t)c0 * 8 + l];
        uint4 x1 = feats16[(size_t)c1 * 8 + l];
        uint4 x2 = feats16[(size_t)c2 * 8 + l];
        uint4 x3 = feats16[(size_t)c3 * 8 + l];
        fma8(sum, w0, x0);
        fma8(sum, w1, x1);
        fma8(sum, w2, x2);
        fma8(sum, w3, x3);
    }
    for (; k < d; ++k) {
        int c = (int)cv[s + k];
        uint4 x = feats16[(size_t)c * 8 + l];
        fma8(sum, invs[c], x);
    }
    float ivr = invs[row];
    uint4 bx = feats16[(size_t)row * 8 + l];
    float base[8] = {bflo(bx.x), bfhi(bx.x), bflo(bx.y), bfhi(bx.y),
                     bflo(bx.z), bfhi(bx.z), bflo(bx.w), bfhi(bx.w)};
    float a[8], fs[8];
    float iv2 = ivr * ivr;
    #pragma unroll
    for (int j = 0; j < 8; ++j) {
        a[j]  = fmaf(ivr, sum[j], base[j]);
        fs[j] = iv2 * sum[j];
    }
    size_t idx = (size_t)row * 8 + l;
    acc16[idx] = pack8(a);
    f1s16[idx] = pack8(fs);
}

// Layer 2: acc16[r] += invs[r] * Σ f1s16[c]
__global__ void layer2_kernel(const int* __restrict__ off,
                              const int* __restrict__ deg,
                              const unsigned int* __restrict__ cv,
                              const float* __restrict__ invs,
                              const uint4* __restrict__ f1s16,
                              uint4* __restrict__ acc16) {
    int wave = blockIdx.x * (blockDim.x >> 6) + (threadIdx.x >> 6);
    int sub  = (threadIdx.x >> 3) & 7;
    int l    = threadIdx.x & 7;
    int row  = wave * 8 + sub;
    if (row >= NTOT) return;
    int s = off[row], d = deg[row];
    float sum[8] = {0.f, 0.f, 0.f, 0.f, 0.f, 0.f, 0.f, 0.f};
    int k = 0;
    for (; k + 4 <= d; k += 4) {
        int c0 = (int)cv[s + k + 0];
        int c1 = (int)cv[s + k + 1];
        int c2 = (int)cv[s + k + 2];
        int c3 = (int)cv[s + k + 3];
        uint4 x0 = f1s16[(size_t)c0 * 8 + l];
        uint4 x1 = f1s16[(size_t)c1 * 8 + l];
        uint4 x2 = f1s16[(size_t)c2 * 8 + l];
        uint4 x3 = f1s16[(size_t)c3 * 8 + l];
        fma8(sum, 1.f, x0);
        fma8(sum, 1.f, x1);
        fma8(sum, 1.f, x2);
        fma8(sum, 1.f, x3);
    }
    for (; k < d; ++k) {
        int c = (int)cv[s + k];
        uint4 x = f1s16[(size_t)c * 8 + l];
        fma8(sum, 1.f, x);
    }
    float ivr = invs[row];
    size_t idx = (size_t)row * 8 + l;
    uint4 ax = acc16[idx];
    float a[8] = {bflo(ax.x), bfhi(ax.x), bflo(ax.y), bfhi(ax.y),
                  bflo(ax.z), bfhi(ax.z), bflo(ax.w), bfhi(ax.w)};
    #pragma unroll
    for (int j = 0; j < 8; ++j) a[j] = fmaf(ivr, sum[j], a[j]);
    acc16[idx] = pack8(a);
}

// ---------------------------------------------------------------------------
// Fused bundle-SpMM + BPR loss + finalize. One wave per sample.
__global__ void score_kernel(const int* __restrict__ offB,
                             const int* __restrict__ degB,
                             const unsigned int* __restrict__ cvB,
                             const uint4* __restrict__ acc16,
                             const int* __restrict__ users,
                             const int* __restrict__ bundles,
                             float* __restrict__ loss_sum,
                             int* __restrict__ done,
                             float* __restrict__ out) {
    int tid  = blockIdx.x * blockDim.x + threadIdx.x;
    int smp  = tid >> 6;
    int lane = threadIdx.x & 63;
    int sub  = lane >> 3;     // 8 subgroups of 8 lanes
    int l    = lane & 7;      // dim slice [l*8, l*8+8)

    float pred[2];
    if (smp < BATCH) {
        int u = users[smp];
        uint4 uv = acc16[(size_t)u * 8 + l];
        float uvals[8] = {bflo(uv.x), bfhi(uv.x), bflo(uv.y), bfhi(uv.y),
                          bflo(uv.z), bfhi(uv.z), bflo(uv.w), bfhi(uv.w)};
        #pragma unroll
        for (int j = 0; j < 2; ++j) {
            int bd = bundles[2 * smp + j];
            int s  = offB[bd];
            int d  = degB[bd];
            float part[8] = {0.f, 0.f, 0.f, 0.f, 0.f, 0.f, 0.f, 0.f};
            for (int k = sub; k < d; k += 8) {
                int c = (int)cvB[s + k];
                uint4 x = acc16[(size_t)(NU_ + c) * 8 + l];
                fma8(part, 1.f, x);
            }
            #pragma unroll
            for (int m = 8; m <= 32; m <<= 1) {
                #pragma unroll
                for (int i = 0; i < 8; ++i)
                    part[i] += __shfl_xor(part[i], m, 64);
            }
            float dp = 0.f;
            #pragma unroll
            for (int i = 0; i < 8; ++i) dp = fmaf(part[i], uvals[i], dp);
            #pragma unroll
            for (int m = 1; m <= 4; m <<= 1)
                dp += __shfl_xor(dp, m, 64);
            pred[j] = dp * (1.0f / 9.0f) / ((float)d + 1e-8f);
        }
        if (lane == 0) {
            float x = pred[0] - pred[1];
            float lv = fmaxf(-x, 0.0f) + log1pf(expf(-fabsf(x)));
            atomicAdd(loss_sum, lv);
        }
    }
    __syncthreads();
    if (threadIdx.x == 0) {
        __threadfence();
        int old = atomicAdd(done, 1);
        if (old == (int)gridDim.x - 1) {
            float total = atomicAdd(loss_sum, 0.0f);   // coherent read
            out[0] = total * (1.0f / BATCH);
            out[1] = 0.0f;
        }
    }
}

// ---------------------------------------------------------------------------
extern "C" void kernel_launch(void* const* d_in, const int* in_sizes, int n_in,
                              void* d_out, int out_size, void* d_ws, size_t ws_size,
                              hipStream_t stream) {
    const float* uf        = (const float*)d_in[0];
    const float* itf       = (const float*)d_in[1];
    const int*   prop_rows = (const int*)  d_in[4];
    const int*   prop_cols = (const int*)  d_in[5];
    const int*   bi_rows   = (const int*)  d_in[6];
    const int*   bi_cols   = (const int*)  d_in[7];
    const int*   users     = (const int*)  d_in[8];
    const int*   bundles   = (const int*)  d_in[9];
    float* out = (float*)d_out;

    char* ws = (char*)d_ws;
    uint4*        acc16    = (uint4*)       (ws + 0);            // 19.2 MB
    uint4*        f1s16    = (uint4*)       (ws + 19200000);     // 19.2 MB
    uint4*        feats16  = (uint4*)       (ws + 38400000);     // 19.2 MB
    unsigned int* binnedP  = (unsigned int*)(ws + 57600000);     // 586*20480*4 = 48.0 MB
    unsigned int* binnedB  = (unsigned int*)(ws + 105605120);    // 79*15360*4 = 4.85 MB
    int*          cellcntP = (int*)         (ws + 110458880);    // 586*512*4 = 1.2 MB
    int*          cellcntB = (int*)         (ws + 111659008);    // 79*96*4 = 30 KB
    int*          degP     = (int*)         (ws + 111689344);
    int*          offP     = (int*)         (ws + 112289344);
    float*        invsP    = (float*)       (ws + 112889344);
    int*          degB     = (int*)         (ws + 113489344);
    int*          offB     = (int*)         (ws + 113569344);
    float*        loss     = (float*)       (ws + 113649344);
    int*          done     = (int*)         (ws + 113649348);

    hipMemsetAsync(loss, 0, 8, stream);   // loss + done

    // 1) fused multisplit (private cells, no atomics) + bf16 cast
    mscast_kernel<<<MS_TOTAL + CAST_BLOCKS, 256, 0, stream>>>(
        prop_rows, prop_cols, bi_rows, bi_cols,
        binnedP, cellcntP, binnedB, cellcntB,
        (const float4*)uf, (const float4*)itf, (uint2*)feats16);

    // 2) per-bin CSR build, in-place via LDS staging (P+B fused)
    bin_csr_kernel<<<NBIN_P + NBIN_B, 256, 0, stream>>>(
        binnedP, cellcntP, offP, degP, invsP,
        binnedB, cellcntB, offB, degB);

    // 3-4) propagation
    layer1_kernel<<<(NTOT + 31) / 32, 256, 0, stream>>>(offP, degP, binnedP, invsP,
                                                        feats16, f1s16, acc16);
    layer2_kernel<<<(NTOT + 31) / 32, 256, 0, stream>>>(offP, degP, binnedP, invsP,
                                                        f1s16, acc16);

    // 5) fused bundle-SpMM + loss + finalize
    score_kernel<<<SCORE_BLOCKS, 256, 0, stream>>>(
        offB, degB, binnedB, acc16, users, bundles, loss, done, out);
}

// Round 14
// 471.279 us; speedup vs baseline: 1.1126x; 1.1126x over previous
//
#include <hip/hip_runtime.h>
#include <math.h>

#define NU_    100000
#define NI_    50000
#define NB_    20000
#define DIM    64
#define E_UI_  2000000
#define E_BI_  600000
#define NPROP  (2 * E_UI_)
#define NTOT   (NU_ + NI_)
#define BATCH  4096
#define NBIN_P ((NTOT + 255) / 256)   // 586
#define NBIN_B ((NB_  + 255) / 256)   // 79

// Private-cell multisplit geometry: binned[bin][block][slot].
// P: lambda = 4M/(512*586) = 10.2 per cell; SLICE_P=40 is +~9 sigma.
// B: lambda = 600K/(96*79) = 79 per cell; SLICE_B=160 is +~9 sigma.
#define VG_P     512
#define SLICE_P  40
#define BINSZ_P  (VG_P * SLICE_P)     // 20480 slots per P bin
#define VG_B     96
#define SLICE_B  160
#define BINSZ_B  (VG_B * SLICE_B)     // 15360 slots per B bin
#define EBUF_CAP 12288                // max valid entries per bin (~10.4K item bins)

#define MS_TOTAL    (VG_B + VG_P)     // 608 multisplit blocks (co-resident)
#define CAST_BLOCKS ((NTOT * 16) / 256)   // 9375 (exact)
#define SCORE_BLOCKS (BATCH / 4)          // 1024, one wave per sample

// ---------------------------------------------------------------------------
// bf16 helpers
__device__ __forceinline__ float bflo(unsigned int u) {
    return __uint_as_float(u << 16);
}
__device__ __forceinline__ float bfhi(unsigned int u) {
    return __uint_as_float(u & 0xFFFF0000u);
}
__device__ __forceinline__ unsigned short f2bf(float f) {         // RNE
    unsigned int u = __float_as_uint(f);
    u += 0x7FFFu + ((u >> 16) & 1u);
    return (unsigned short)(u >> 16);
}
__device__ __forceinline__ unsigned int pack2(float a, float b) {
    return (unsigned int)f2bf(a) | ((unsigned int)f2bf(b) << 16);
}

// ---------------------------------------------------------------------------
// Fused multisplit (private cells, ZERO global atomics) + bf16 cast.
// Block order: [B: 0..96) [P: 96..608) [cast: 608..9983).
// payload = ((row & 255) << 24) | col
__global__ void mscast_kernel(const int* __restrict__ prows,
                              const int* __restrict__ pcols,
                              const int* __restrict__ brows,
                              const int* __restrict__ bcols,
                              unsigned int* __restrict__ binnedP,
                              int* __restrict__ cellcntP,
                              unsigned int* __restrict__ binnedB,
                              int* __restrict__ cellcntB,
                              const float4* __restrict__ uf4,
                              const float4* __restrict__ itf4,
                              uint2* __restrict__ feats_out) {
    constexpr int BUF = 16;
    __shared__ int cnt[NBIN_P];                 // staged-but-unflushed count
    __shared__ int fpos[NBIN_P];                // flushed count (cell-relative)
    __shared__ int basep[NBIN_P];               // flush base for current phase
    __shared__ unsigned int stage[NBIN_P][BUF];
    int bid = blockIdx.x;
    if (bid >= MS_TOTAL) {
        // ---- cast lane ----
        int i = (bid - MS_TOTAL) * 256 + threadIdx.x;
        const int nuq = NU_ * 16;
        const int totq = NTOT * 16;
        if (i < totq) {
            float4 v = (i < nuq) ? uf4[i] : itf4[i - nuq];
            uint2 o;
            o.x = pack2(v.x, v.y);
            o.y = pack2(v.z, v.w);
            feats_out[i] = o;
        }
        return;
    }
    const int *rows, *cols; int n, nbin, vb, vgrid, slice; size_t binsz;
    unsigned int* binned; int* cellcnt;
    if (bid < VG_B) {
        rows = brows; cols = bcols; n = E_BI_; nbin = NBIN_B;
        vb = bid; vgrid = VG_B; slice = SLICE_B; binsz = BINSZ_B;
        binned = binnedB; cellcnt = cellcntB;
    } else {
        rows = prows; cols = pcols; n = NPROP; nbin = NBIN_P;
        vb = bid - VG_B; vgrid = VG_P; slice = SLICE_P; binsz = BINSZ_P;
        binned = binnedP; cellcnt = cellcntP;
    }
    for (int i = threadIdx.x; i < nbin; i += 256) { cnt[i] = 0; fpos[i] = 0; }
    __syncthreads();
    int stride = vgrid * 1024;
    for (int base = vb * 1024; base < n; base += stride) {
        int bin[4], pos[4];
        unsigned int payload[4];
        #pragma unroll
        for (int j = 0; j < 4; ++j) {
            int i = base + j * 256 + threadIdx.x;   // coalesced per step
            pos[j] = -1;
            if (i < n) {
                int r = rows[i];
                int c = cols[i];
                bin[j] = r >> 8;
                payload[j] = ((unsigned int)(r & 255) << 24) | (unsigned int)c;
                pos[j] = atomicAdd(&cnt[bin[j]], 1);
                if (pos[j] < BUF) stage[bin[j]][pos[j]] = payload[j];
            }
        }
        __syncthreads();
        #pragma unroll
        for (int j = 0; j < 4; ++j)
            if (pos[j] == BUF) {               // unique leader per bin per phase
                basep[bin[j]] = fpos[bin[j]];
                fpos[bin[j]] += cnt[bin[j]];
            }
        __syncthreads();
        #pragma unroll
        for (int j = 0; j < 4; ++j) {
            if (pos[j] >= BUF) {
                size_t cb = (size_t)bin[j] * binsz + (size_t)vb * slice;
                int rel = basep[bin[j]] + pos[j];
                if (rel < slice) binned[cb + rel] = payload[j];
                if (pos[j] == BUF) {
                    int b0 = basep[bin[j]];
                    #pragma unroll
                    for (int q = 0; q < BUF; ++q)
                        if (b0 + q < slice) binned[cb + b0 + q] = stage[bin[j]][q];
                    cnt[bin[j]] = 0;
                }
            }
        }
        __syncthreads();
    }
    // drain residual staged entries + write exact cell counts
    for (int b = threadIdx.x; b < nbin; b += 256) {
        int c = cnt[b];
        int f = fpos[b];
        size_t cb = (size_t)b * binsz + (size_t)vb * slice;
        for (int j = 0; j < c && f + j < slice; ++j) binned[cb + f + j] = stage[b][j];
        int tot = f + c;
        if (tot > slice) tot = slice;
        cellcnt[b * vgrid + vb] = tot;
    }
}

// ---------------------------------------------------------------------------
// Per-bin CSR build. Coalesced predicated sweep over the bin's whole fixed
// region compacts valid entries into LDS (no serial cell walks), then
// hist/scan/in-place fill. cv aliases binned (reads precede writes).
template<int VGRID, int SLICE>
__device__ __forceinline__ void bin_csr_body(unsigned int* __restrict__ binned,
                                             const int* __restrict__ cellcnt,
                                             int* __restrict__ off,
                                             int* __restrict__ deg,
                                             float* __restrict__ invs,
                                             int b, int nrows,
                                             unsigned int* ebuf, int* ccnt,
                                             int* cstart, int* s2, int* cnt,
                                             int* cur, int* scanbuf) {
    int t = threadIdx.x;
    int rowbase = b << 8;
    for (int i = t; i < VGRID; i += 256) ccnt[i] = cellcnt[b * VGRID + i];
    __syncthreads();
    // exclusive scan of ccnt (VGRID <= 512) via pair-sum + 256-scan
    int a0 = (2 * t     < VGRID) ? ccnt[2 * t]     : 0;
    int a1 = (2 * t + 1 < VGRID) ? ccnt[2 * t + 1] : 0;
    s2[t] = a0 + a1;
    __syncthreads();
    for (int o = 1; o < 256; o <<= 1) {
        int y = (t >= o) ? s2[t - o] : 0;
        __syncthreads();
        s2[t] += y;
        __syncthreads();
    }
    int e2 = s2[t] - (a0 + a1);
    if (2 * t     < VGRID) cstart[2 * t]     = e2;
    if (2 * t + 1 < VGRID) cstart[2 * t + 1] = e2 + a0;
    cnt[t] = 0;
    __syncthreads();
    int m = s2[255];
    if (m > EBUF_CAP) m = EBUF_CAP;
    size_t gbase = (size_t)b * (VGRID * SLICE);
    // coalesced predicated compaction sweep (SLICE is compile-time: magic-mul)
    for (int idx = t; idx < VGRID * SLICE; idx += 256) {
        unsigned int p = binned[gbase + idx];
        int cell = idx / SLICE;
        int rel  = idx - cell * SLICE;
        if (rel < ccnt[cell]) {
            int dst = cstart[cell] + rel;
            if (dst < EBUF_CAP) ebuf[dst] = p;
        }
    }
    __syncthreads();
    // per-row histogram
    for (int i = t; i < m; i += 256)
        atomicAdd(&cnt[ebuf[i] >> 24], 1);
    __syncthreads();
    int x = cnt[t];
    scanbuf[t] = x;
    __syncthreads();
    for (int o = 1; o < 256; o <<= 1) {
        int y = (t >= o) ? scanbuf[t - o] : 0;
        __syncthreads();
        scanbuf[t] += y;
        __syncthreads();
    }
    int base = scanbuf[t] - x;    // bin-local compact offset
    cur[t] = base;
    if (rowbase + t < nrows) {
        off[rowbase + t] = (int)gbase + base;
        deg[rowbase + t] = x;
        if (invs) invs[rowbase + t] = 1.0f / (sqrtf((float)x) + 1e-8f);
    }
    __syncthreads();
    // in-place compacted cv fill from LDS copy
    for (int i = t; i < m; i += 256) {
        unsigned int p = ebuf[i];
        int slot = atomicAdd(&cur[p >> 24], 1);
        binned[gbase + slot] = p & 0xFFFFFFu;
    }
}

__global__ __launch_bounds__(256) void bin_csr_kernel(
        unsigned int* __restrict__ binnedP, const int* __restrict__ cellcntP,
        int* __restrict__ offP, int* __restrict__ degP, float* __restrict__ invsP,
        unsigned int* __restrict__ binnedB, const int* __restrict__ cellcntB,
        int* __restrict__ offB, int* __restrict__ degB) {
    __shared__ unsigned int ebuf[EBUF_CAP];    // 48 KB
    __shared__ int ccnt[VG_P];                 // 2 KB
    __shared__ int cstart[VG_P];               // 2 KB
    __shared__ int s2[256];
    __shared__ int cnt[256];
    __shared__ int cur[256];
    __shared__ int scanbuf[256];
    if (blockIdx.x < NBIN_P)
        bin_csr_body<VG_P, SLICE_P>(binnedP, cellcntP, offP, degP, invsP,
                                    blockIdx.x, NTOT,
                                    ebuf, ccnt, cstart, s2, cnt, cur, scanbuf);
    else
        bin_csr_body<VG_B, SLICE_B>(binnedB, cellcntB, offB, degB, (float*)0,
                                    blockIdx.x - NBIN_P, NB_,
                                    ebuf, ccnt, cstart, s2, cnt, cur, scanbuf);
}

// ---------------------------------------------------------------------------
// 8 lanes/row, uint4 = 8 bf16 per lane. 8 rows/wave, 32 rows per 256-block.
__device__ __forceinline__ void fma8(float* s, float v, uint4 x) {
    s[0] = fmaf(v, bflo(x.x), s[0]);
    s[1] = fmaf(v, bfhi(x.x), s[1]);
    s[2] = fmaf(v, bflo(x.y), s[2]);
    s[3] = fmaf(v, bfhi(x.y), s[3]);
    s[4] = fmaf(v, bflo(x.z), s[4]);
    s[5] = fmaf(v, bfhi(x.z), s[5]);
    s[6] = fmaf(v, bflo(x.w), s[6]);
    s[7] = fmaf(v, bfhi(x.w), s[7]);
}
__device__ __forceinline__ uint4 pack8(const float* s) {
    uint4 o;
    o.x = pack2(s[0], s[1]);
    o.y = pack2(s[2], s[3]);
    o.z = pack2(s[4], s[5]);
    o.w = pack2(s[6], s[7]);
    return o;
}

// Layer 1: sum = Σ invs[c]·feats[c]; acc16[r] = feats[r] + invs[r]·sum;
//          f1s16[r] = invs[r]²·sum
__global__ void layer1_kernel(const int* __restrict__ off,
                              const int* __restrict__ deg,
                              const unsigned int* __restrict__ cv,
                              const float* __restrict__ invs,
                              const uint4* __restrict__ feats16,
                              uint4* __restrict__ f1s16,
                              uint4* __restrict__ acc16) {
    int wave = blockIdx.x * (blockDim.x >> 6) + (threadIdx.x >> 6);
    int sub  = (threadIdx.x >> 3) & 7;
    int l    = threadIdx.x & 7;
    int row  = wave * 8 + sub;
    if (row >= NTOT) return;
    int s = off[row], d = deg[row];
    float sum[8] = {0.f, 0.f, 0.f, 0.f, 0.f, 0.f, 0.f, 0.f};
    int k = 0;
    for (; k + 4 <= d; k += 4) {
        int c0 = (int)cv[s + k + 0];
        int c1 = (int)cv[s + k + 1];
        int c2 = (int)cv[s + k + 2];
        int c3 = (int)cv[s + k + 3];
        float w0 = invs[c0], w1 = invs[c1], w2 = invs[c2], w3 = invs[c3];
        uint4 x0 = feats16[(size_t)c0 * 8 + l];
        uint4 x1 = feats16[(size_t)c1 * 8 + l];
        uint4 x2 = feats16[(size_t)c2 * 8 + l];
        uint4 x3 = feats16[(size_t)c3 * 8 + l];
        fma8(sum, w0, x0);
        fma8(sum, w1, x1);
        fma8(sum, w2, x2);
        fma8(sum, w3, x3);
    }
    for (; k < d; ++k) {
        int c = (int)cv[s + k];
        uint4 x = feats16[(size_t)c * 8 + l];
        fma8(sum, invs[c], x);
    }
    float ivr = invs[row];
    uint4 bx = feats16[(size_t)row * 8 + l];
    float base[8] = {bflo(bx.x), bfhi(bx.x), bflo(bx.y), bfhi(bx.y),
                     bflo(bx.z), bfhi(bx.z), bflo(bx.w), bfhi(bx.w)};
    float a[8], fs[8];
    float iv2 = ivr * ivr;
    #pragma unroll
    for (int j = 0; j < 8; ++j) {
        a[j]  = fmaf(ivr, sum[j], base[j]);
        fs[j] = iv2 * sum[j];
    }
    size_t idx = (size_t)row * 8 + l;
    acc16[idx] = pack8(a);
    f1s16[idx] = pack8(fs);
}

// Layer 2: acc16[r] += invs[r] * Σ f1s16[c]
__global__ void layer2_kernel(const int* __restrict__ off,
                              const int* __restrict__ deg,
                              const unsigned int* __restrict__ cv,
                              const float* __restrict__ invs,
                              const uint4* __restrict__ f1s16,
                              uint4* __restrict__ acc16) {
    int wave = blockIdx.x * (blockDim.x >> 6) + (threadIdx.x >> 6);
    int sub  = (threadIdx.x >> 3) & 7;
    int l    = threadIdx.x & 7;
    int row  = wave * 8 + sub;
    if (row >= NTOT) return;
    int s = off[row], d = deg[row];
    float sum[8] = {0.f, 0.f, 0.f, 0.f, 0.f, 0.f, 0.f, 0.f};
    int k = 0;
    for (; k + 4 <= d; k += 4) {
        int c0 = (int)cv[s + k + 0];
        int c1 = (int)cv[s + k + 1];
        int c2 = (int)cv[s + k + 2];
        int c3 = (int)cv[s + k + 3];
        uint4 x0 = f1s16[(size_t)c0 * 8 + l];
        uint4 x1 = f1s16[(size_t)c1 * 8 + l];
        uint4 x2 = f1s16[(size_t)c2 * 8 + l];
        uint4 x3 = f1s16[(size_t)c3 * 8 + l];
        fma8(sum, 1.f, x0);
        fma8(sum, 1.f, x1);
        fma8(sum, 1.f, x2);
        fma8(sum, 1.f, x3);
    }
    for (; k < d; ++k) {
        int c = (int)cv[s + k];
        uint4 x = f1s16[(size_t)c * 8 + l];
        fma8(sum, 1.f, x);
    }
    float ivr = invs[row];
    size_t idx = (size_t)row * 8 + l;
    uint4 ax = acc16[idx];
    float a[8] = {bflo(ax.x), bfhi(ax.x), bflo(ax.y), bfhi(ax.y),
                  bflo(ax.z), bfhi(ax.z), bflo(ax.w), bfhi(ax.w)};
    #pragma unroll
    for (int j = 0; j < 8; ++j) a[j] = fmaf(ivr, sum[j], a[j]);
    acc16[idx] = pack8(a);
}

// ---------------------------------------------------------------------------
// Fused bundle-SpMM + BPR loss + finalize. One wave per sample.
__global__ void score_kernel(const int* __restrict__ offB,
                             const int* __restrict__ degB,
                             const unsigned int* __restrict__ cvB,
                             const uint4* __restrict__ acc16,
                             const int* __restrict__ users,
                             const int* __restrict__ bundles,
                             float* __restrict__ loss_sum,
                             int* __restrict__ done,
                             float* __restrict__ out) {
    int tid  = blockIdx.x * blockDim.x + threadIdx.x;
    int smp  = tid >> 6;
    int lane = threadIdx.x & 63;
    int sub  = lane >> 3;     // 8 subgroups of 8 lanes
    int l    = lane & 7;      // dim slice [l*8, l*8+8)

    float pred[2];
    if (smp < BATCH) {
        int u = users[smp];
        uint4 uv = acc16[(size_t)u * 8 + l];
        float uvals[8] = {bflo(uv.x), bfhi(uv.x), bflo(uv.y), bfhi(uv.y),
                          bflo(uv.z), bfhi(uv.z), bflo(uv.w), bfhi(uv.w)};
        #pragma unroll
        for (int j = 0; j < 2; ++j) {
            int bd = bundles[2 * smp + j];
            int s  = offB[bd];
            int d  = degB[bd];
            float part[8] = {0.f, 0.f, 0.f, 0.f, 0.f, 0.f, 0.f, 0.f};
            for (int k = sub; k < d; k += 8) {
                int c = (int)cvB[s + k];
                uint4 x = acc16[(size_t)(NU_ + c) * 8 + l];
                fma8(part, 1.f, x);
            }
            #pragma unroll
            for (int m = 8; m <= 32; m <<= 1) {
                #pragma unroll
                for (int i = 0; i < 8; ++i)
                    part[i] += __shfl_xor(part[i], m, 64);
            }
            float dp = 0.f;
            #pragma unroll
            for (int i = 0; i < 8; ++i) dp = fmaf(part[i], uvals[i], dp);
            #pragma unroll
            for (int m = 1; m <= 4; m <<= 1)
                dp += __shfl_xor(dp, m, 64);
            pred[j] = dp * (1.0f / 9.0f) / ((float)d + 1e-8f);
        }
        if (lane == 0) {
            float x = pred[0] - pred[1];
            float lv = fmaxf(-x, 0.0f) + log1pf(expf(-fabsf(x)));
            atomicAdd(loss_sum, lv);
        }
    }
    __syncthreads();
    if (threadIdx.x == 0) {
        __threadfence();
        int old = atomicAdd(done, 1);
        if (old == (int)gridDim.x - 1) {
            float total = atomicAdd(loss_sum, 0.0f);   // coherent read
            out[0] = total * (1.0f / BATCH);
            out[1] = 0.0f;
        }
    }
}

// ---------------------------------------------------------------------------
extern "C" void kernel_launch(void* const* d_in, const int* in_sizes, int n_in,
                              void* d_out, int out_size, void* d_ws, size_t ws_size,
                              hipStream_t stream) {
    const float* uf        = (const float*)d_in[0];
    const float* itf       = (const float*)d_in[1];
    const int*   prop_rows = (const int*)  d_in[4];
    const int*   prop_cols = (const int*)  d_in[5];
    const int*   bi_rows   = (const int*)  d_in[6];
    const int*   bi_cols   = (const int*)  d_in[7];
    const int*   users     = (const int*)  d_in[8];
    const int*   bundles   = (const int*)  d_in[9];
    float* out = (float*)d_out;

    char* ws = (char*)d_ws;
    uint4*        acc16    = (uint4*)       (ws + 0);            // 19.2 MB
    uint4*        f1s16    = (uint4*)       (ws + 19200000);     // 19.2 MB
    uint4*        feats16  = (uint4*)       (ws + 38400000);     // 19.2 MB
    unsigned int* binnedP  = (unsigned int*)(ws + 57600000);     // 586*20480*4 = 48.0 MB
    unsigned int* binnedB  = (unsigned int*)(ws + 105605120);    // 79*15360*4 = 4.85 MB
    int*          cellcntP = (int*)         (ws + 110458880);    // 586*512*4 = 1.2 MB
    int*          cellcntB = (int*)         (ws + 111659008);    // 79*96*4 = 30 KB
    int*          degP     = (int*)         (ws + 111689344);
    int*          offP     = (int*)         (ws + 112289344);
    float*        invsP    = (float*)       (ws + 112889344);
    int*          degB     = (int*)         (ws + 113489344);
    int*          offB     = (int*)         (ws + 113569344);
    float*        loss     = (float*)       (ws + 113649344);
    int*          done     = (int*)         (ws + 113649348);

    hipMemsetAsync(loss, 0, 8, stream);   // loss + done

    // 1) fused multisplit (private cells, no atomics) + bf16 cast
    mscast_kernel<<<MS_TOTAL + CAST_BLOCKS, 256, 0, stream>>>(
        prop_rows, prop_cols, bi_rows, bi_cols,
        binnedP, cellcntP, binnedB, cellcntB,
        (const float4*)uf, (const float4*)itf, (uint2*)feats16);

    // 2) per-bin CSR build, coalesced compaction sweep, in-place (P+B fused)
    bin_csr_kernel<<<NBIN_P + NBIN_B, 256, 0, stream>>>(
        binnedP, cellcntP, offP, degP, invsP,
        binnedB, cellcntB, offB, degB);

    // 3-4) propagation
    layer1_kernel<<<(NTOT + 31) / 32, 256, 0, stream>>>(offP, degP, binnedP, invsP,
                                                        feats16, f1s16, acc16);
    layer2_kernel<<<(NTOT + 31) / 32, 256, 0, stream>>>(offP, degP, binnedP, invsP,
                                                        f1s16, acc16);

    // 5) fused bundle-SpMM + loss + finalize
    score_kernel<<<SCORE_BLOCKS, 256, 0, stream>>>(
        offB, degB, binnedB, acc16, users, bundles, loss, done, out);
}

// Round 15
// 445.669 us; speedup vs baseline: 1.1765x; 1.0575x over previous
//
#include <hip/hip_runtime.h>
#include <math.h>

#define NU_    100000
#define NI_    50000
#define NB_    20000
#define DIM    64
#define E_UI_  2000000
#define E_BI_  600000
#define NPROP  (2 * E_UI_)
#define NTOT   (NU_ + NI_)
#define BATCH  4096
#define NBIN_P ((NTOT + 255) / 256)   // 586
#define NBIN_B ((NB_  + 255) / 256)   // 79

// Private-cell multisplit geometry: binned[bin][block][slot].
#define VG_P     512
#define SLICE_P  40
#define BINSZ_P  (VG_P * SLICE_P)     // 20480 slots per P bin
#define VG_B     96
#define SLICE_B  160
#define BINSZ_B  (VG_B * SLICE_B)     // 15360 slots per B bin
#define EBUF_CAP 12288                // max valid entries per bin

#define MS_TOTAL    (VG_B + VG_P)     // 608 multisplit blocks (co-resident)
#define CAST_BLOCKS ((NTOT * 16) / 256)   // 9375 (exact)
#define SCORE_BLOCKS (BATCH / 4)          // 1024, one wave per sample

// ---------------------------------------------------------------------------
// bf16 helpers
__device__ __forceinline__ float bflo(unsigned int u) {
    return __uint_as_float(u << 16);
}
__device__ __forceinline__ float bfhi(unsigned int u) {
    return __uint_as_float(u & 0xFFFF0000u);
}
__device__ __forceinline__ unsigned short f2bf(float f) {         // RNE
    unsigned int u = __float_as_uint(f);
    u += 0x7FFFu + ((u >> 16) & 1u);
    return (unsigned short)(u >> 16);
}
__device__ __forceinline__ unsigned int pack2(float a, float b) {
    return (unsigned int)f2bf(a) | ((unsigned int)f2bf(b) << 16);
}

// ---------------------------------------------------------------------------
// Fused multisplit (private cells, ZERO global atomics) + bf16 cast.
// Block order: [B: 0..96) [P: 96..608) [cast: 608..9983).
// payload = ((row & 255) << 24) | col
__global__ void mscast_kernel(const int* __restrict__ prows,
                              const int* __restrict__ pcols,
                              const int* __restrict__ brows,
                              const int* __restrict__ bcols,
                              unsigned int* __restrict__ binnedP,
                              int* __restrict__ cellcntP,
                              unsigned int* __restrict__ binnedB,
                              int* __restrict__ cellcntB,
                              const float4* __restrict__ uf4,
                              const float4* __restrict__ itf4,
                              uint2* __restrict__ feats_out) {
    constexpr int BUF = 16;
    __shared__ int cnt[NBIN_P];                 // staged-but-unflushed count
    __shared__ int fpos[NBIN_P];                // flushed count (cell-relative)
    __shared__ int basep[NBIN_P];               // flush base for current phase
    __shared__ unsigned int stage[NBIN_P][BUF];
    int bid = blockIdx.x;
    if (bid >= MS_TOTAL) {
        // ---- cast lane ----
        int i = (bid - MS_TOTAL) * 256 + threadIdx.x;
        const int nuq = NU_ * 16;
        const int totq = NTOT * 16;
        if (i < totq) {
            float4 v = (i < nuq) ? uf4[i] : itf4[i - nuq];
            uint2 o;
            o.x = pack2(v.x, v.y);
            o.y = pack2(v.z, v.w);
            feats_out[i] = o;
        }
        return;
    }
    const int *rows, *cols; int n, nbin, vb, vgrid, slice; size_t binsz;
    unsigned int* binned; int* cellcnt;
    if (bid < VG_B) {
        rows = brows; cols = bcols; n = E_BI_; nbin = NBIN_B;
        vb = bid; vgrid = VG_B; slice = SLICE_B; binsz = BINSZ_B;
        binned = binnedB; cellcnt = cellcntB;
    } else {
        rows = prows; cols = pcols; n = NPROP; nbin = NBIN_P;
        vb = bid - VG_B; vgrid = VG_P; slice = SLICE_P; binsz = BINSZ_P;
        binned = binnedP; cellcnt = cellcntP;
    }
    for (int i = threadIdx.x; i < nbin; i += 256) { cnt[i] = 0; fpos[i] = 0; }
    __syncthreads();
    int stride = vgrid * 1024;
    for (int base = vb * 1024; base < n; base += stride) {
        int bin[4], pos[4];
        unsigned int payload[4];
        #pragma unroll
        for (int j = 0; j < 4; ++j) {
            int i = base + j * 256 + threadIdx.x;   // coalesced per step
            pos[j] = -1;
            if (i < n) {
                int r = rows[i];
                int c = cols[i];
                bin[j] = r >> 8;
                payload[j] = ((unsigned int)(r & 255) << 24) | (unsigned int)c;
                pos[j] = atomicAdd(&cnt[bin[j]], 1);
                if (pos[j] < BUF) stage[bin[j]][pos[j]] = payload[j];
            }
        }
        __syncthreads();
        #pragma unroll
        for (int j = 0; j < 4; ++j)
            if (pos[j] == BUF) {               // unique leader per bin per phase
                basep[bin[j]] = fpos[bin[j]];
                fpos[bin[j]] += cnt[bin[j]];
            }
        __syncthreads();
        #pragma unroll
        for (int j = 0; j < 4; ++j) {
            if (pos[j] >= BUF) {
                size_t cb = (size_t)bin[j] * binsz + (size_t)vb * slice;
                int rel = basep[bin[j]] + pos[j];
                if (rel < slice) binned[cb + rel] = payload[j];
                if (pos[j] == BUF) {
                    int b0 = basep[bin[j]];
                    #pragma unroll
                    for (int q = 0; q < BUF; ++q)
                        if (b0 + q < slice) binned[cb + b0 + q] = stage[bin[j]][q];
                    cnt[bin[j]] = 0;
                }
            }
        }
        __syncthreads();
    }
    // drain residual staged entries + write exact cell counts
    for (int b = threadIdx.x; b < nbin; b += 256) {
        int c = cnt[b];
        int f = fpos[b];
        size_t cb = (size_t)b * binsz + (size_t)vb * slice;
        for (int j = 0; j < c && f + j < slice; ++j) binned[cb + f + j] = stage[b][j];
        int tot = f + c;
        if (tot > slice) tot = slice;
        cellcnt[b * vgrid + vb] = tot;
    }
}

// ---------------------------------------------------------------------------
// Per-bin CSR build, 512 threads/block. Two predicated coalesced sweeps:
// (1) row histogram, (2) direct placement into ebuf via LDS row cursors.
// Final coalesced dump ebuf -> binned prefix (in-place safe: all global
// reads complete before any global write).
template<int VGRID, int SLICE>
__device__ __forceinline__ void bin_csr_body(unsigned int* __restrict__ binned,
                                             const int* __restrict__ cellcnt,
                                             int* __restrict__ off,
                                             int* __restrict__ deg,
                                             float* __restrict__ invs,
                                             int b, int nrows,
                                             unsigned int* ebuf, int* ccnt,
                                             int* cnt, int* cur, int* scanbuf) {
    const int TB = 512;
    int t = threadIdx.x;
    int rowbase = b << 8;
    for (int i = t; i < VGRID; i += TB) ccnt[i] = cellcnt[b * VGRID + i];
    if (t < 256) cnt[t] = 0;
    __syncthreads();
    size_t gbase = (size_t)b * (VGRID * SLICE);
    // sweep 1: row histogram (coalesced, predicated)
    for (int idx = t; idx < VGRID * SLICE; idx += TB) {
        unsigned int p = binned[gbase + idx];
        int cell = idx / SLICE;
        int rel  = idx - cell * SLICE;
        if (rel < ccnt[cell]) atomicAdd(&cnt[p >> 24], 1);
    }
    __syncthreads();
    // exclusive scan of 256 row counts
    int x = 0;
    if (t < 256) { x = cnt[t]; scanbuf[t] = x; }
    __syncthreads();
    for (int o = 1; o < 256; o <<= 1) {
        int y = 0;
        if (t < 256 && t >= o) y = scanbuf[t - o];
        __syncthreads();
        if (t < 256) scanbuf[t] += y;
        __syncthreads();
    }
    if (t < 256) {
        int base = scanbuf[t] - x;        // bin-local compact offset
        cur[t] = base;
        if (rowbase + t < nrows) {
            off[rowbase + t] = (int)gbase + base;
            deg[rowbase + t] = x;
            if (invs) invs[rowbase + t] = 1.0f / (sqrtf((float)x) + 1e-8f);
        }
    }
    __syncthreads();
    int m = scanbuf[255];
    if (m > EBUF_CAP) m = EBUF_CAP;
    // sweep 2: place cols into ebuf (region is L2-hot from sweep 1)
    for (int idx = t; idx < VGRID * SLICE; idx += TB) {
        unsigned int p = binned[gbase + idx];
        int cell = idx / SLICE;
        int rel  = idx - cell * SLICE;
        if (rel < ccnt[cell]) {
            int slot = atomicAdd(&cur[p >> 24], 1);
            if (slot < EBUF_CAP) ebuf[slot] = p & 0xFFFFFFu;
        }
    }
    __syncthreads();
    // coalesced dump of the compacted prefix
    for (int i = t; i < m; i += TB) binned[gbase + i] = ebuf[i];
}

__global__ __launch_bounds__(512) void bin_csr_kernel(
        unsigned int* __restrict__ binnedP, const int* __restrict__ cellcntP,
        int* __restrict__ offP, int* __restrict__ degP, float* __restrict__ invsP,
        unsigned int* __restrict__ binnedB, const int* __restrict__ cellcntB,
        int* __restrict__ offB, int* __restrict__ degB) {
    __shared__ unsigned int ebuf[EBUF_CAP];    // 48 KB
    __shared__ int ccnt[VG_P];                 // 2 KB
    __shared__ int cnt[256];
    __shared__ int cur[256];
    __shared__ int scanbuf[256];
    if (blockIdx.x < NBIN_P)
        bin_csr_body<VG_P, SLICE_P>(binnedP, cellcntP, offP, degP, invsP,
                                    blockIdx.x, NTOT,
                                    ebuf, ccnt, cnt, cur, scanbuf);
    else
        bin_csr_body<VG_B, SLICE_B>(binnedB, cellcntB, offB, degB, (float*)0,
                                    blockIdx.x - NBIN_P, NB_,
                                    ebuf, ccnt, cnt, cur, scanbuf);
}

// ---------------------------------------------------------------------------
// 8 lanes/row, uint4 = 8 bf16 per lane. 8 rows/wave, 32 rows per 256-block.
__device__ __forceinline__ void fma8(float* s, float v, uint4 x) {
    s[0] = fmaf(v, bflo(x.x), s[0]);
    s[1] = fmaf(v, bfhi(x.x), s[1]);
    s[2] = fmaf(v, bflo(x.y), s[2]);
    s[3] = fmaf(v, bfhi(x.y), s[3]);
    s[4] = fmaf(v, bflo(x.z), s[4]);
    s[5] = fmaf(v, bfhi(x.z), s[5]);
    s[6] = fmaf(v, bflo(x.w), s[6]);
    s[7] = fmaf(v, bfhi(x.w), s[7]);
}
__device__ __forceinline__ uint4 pack8(const float* s) {
    uint4 o;
    o.x = pack2(s[0], s[1]);
    o.y = pack2(s[2], s[3]);
    o.z = pack2(s[4], s[5]);
    o.w = pack2(s[6], s[7]);
    return o;
}

// Layer 1: sum = Σ invs[c]·feats[c]; acc16[r] = feats[r] + invs[r]·sum;
//          f1s16[r] = invs[r]²·sum
__global__ void layer1_kernel(const int* __restrict__ off,
                              const int* __restrict__ deg,
                              const unsigned int* __restrict__ cv,
                              const float* __restrict__ invs,
                              const uint4* __restrict__ feats16,
                              uint4* __restrict__ f1s16,
                              uint4* __restrict__ acc16) {
    int wave = blockIdx.x * (blockDim.x >> 6) + (threadIdx.x >> 6);
    int sub  = (threadIdx.x >> 3) & 7;
    int l    = threadIdx.x & 7;
    int row  = wave * 8 + sub;
    if (row >= NTOT) return;
    int s = off[row], d = deg[row];
    float sum[8] = {0.f, 0.f, 0.f, 0.f, 0.f, 0.f, 0.f, 0.f};
    int k = 0;
    for (; k + 4 <= d; k += 4) {
        int c0 = (int)cv[s + k + 0];
        int c1 = (int)cv[s + k + 1];
        int c2 = (int)cv[s + k + 2];
        int c3 = (int)cv[s + k + 3];
        float w0 = invs[c0], w1 = invs[c1], w2 = invs[c2], w3 = invs[c3];
        uint4 x0 = feats16[(size_t)c0 * 8 + l];
        uint4 x1 = feats16[(size_t)c1 * 8 + l];
        uint4 x2 = feats16[(size_t)c2 * 8 + l];
        uint4 x3 = feats16[(size_t)c3 * 8 + l];
        fma8(sum, w0, x0);
        fma8(sum, w1, x1);
        fma8(sum, w2, x2);
        fma8(sum, w3, x3);
    }
    for (; k < d; ++k) {
        int c = (int)cv[s + k];
        uint4 x = feats16[(size_t)c * 8 + l];
        fma8(sum, invs[c], x);
    }
    float ivr = invs[row];
    uint4 bx = feats16[(size_t)row * 8 + l];
    float base[8] = {bflo(bx.x), bfhi(bx.x), bflo(bx.y), bfhi(bx.y),
                     bflo(bx.z), bfhi(bx.z), bflo(bx.w), bfhi(bx.w)};
    float a[8], fs[8];
    float iv2 = ivr * ivr;
    #pragma unroll
    for (int j = 0; j < 8; ++j) {
        a[j]  = fmaf(ivr, sum[j], base[j]);
        fs[j] = iv2 * sum[j];
    }
    size_t idx = (size_t)row * 8 + l;
    acc16[idx] = pack8(a);
    f1s16[idx] = pack8(fs);
}

// Layer 2: acc16[r] += invs[r] * Σ f1s16[c]
__global__ void layer2_kernel(const int* __restrict__ off,
                              const int* __restrict__ deg,
                              const unsigned int* __restrict__ cv,
                              const float* __restrict__ invs,
                              const uint4* __restrict__ f1s16,
                              uint4* __restrict__ acc16) {
    int wave = blockIdx.x * (blockDim.x >> 6) + (threadIdx.x >> 6);
    int sub  = (threadIdx.x >> 3) & 7;
    int l    = threadIdx.x & 7;
    int row  = wave * 8 + sub;
    if (row >= NTOT) return;
    int s = off[row], d = deg[row];
    float sum[8] = {0.f, 0.f, 0.f, 0.f, 0.f, 0.f, 0.f, 0.f};
    int k = 0;
    for (; k + 4 <= d; k += 4) {
        int c0 = (int)cv[s + k + 0];
        int c1 = (int)cv[s + k + 1];
        int c2 = (int)cv[s + k + 2];
        int c3 = (int)cv[s + k + 3];
        uint4 x0 = f1s16[(size_t)c0 * 8 + l];
        uint4 x1 = f1s16[(size_t)c1 * 8 + l];
        uint4 x2 = f1s16[(size_t)c2 * 8 + l];
        uint4 x3 = f1s16[(size_t)c3 * 8 + l];
        fma8(sum, 1.f, x0);
        fma8(sum, 1.f, x1);
        fma8(sum, 1.f, x2);
        fma8(sum, 1.f, x3);
    }
    for (; k < d; ++k) {
        int c = (int)cv[s + k];
        uint4 x = f1s16[(size_t)c * 8 + l];
        fma8(sum, 1.f, x);
    }
    float ivr = invs[row];
    size_t idx = (size_t)row * 8 + l;
    uint4 ax = acc16[idx];
    float a[8] = {bflo(ax.x), bfhi(ax.x), bflo(ax.y), bfhi(ax.y),
                  bflo(ax.z), bfhi(ax.z), bflo(ax.w), bfhi(ax.w)};
    #pragma unroll
    for (int j = 0; j < 8; ++j) a[j] = fmaf(ivr, sum[j], a[j]);
    acc16[idx] = pack8(a);
}

// ---------------------------------------------------------------------------
// Fused bundle-SpMM + BPR loss + finalize. One wave per sample.
__global__ void score_kernel(const int* __restrict__ offB,
                             const int* __restrict__ degB,
                             const unsigned int* __restrict__ cvB,
                             const uint4* __restrict__ acc16,
                             const int* __restrict__ users,
                             const int* __restrict__ bundles,
                             float* __restrict__ loss_sum,
                             int* __restrict__ done,
                             float* __restrict__ out) {
    int tid  = blockIdx.x * blockDim.x + threadIdx.x;
    int smp  = tid >> 6;
    int lane = threadIdx.x & 63;
    int sub  = lane >> 3;     // 8 subgroups of 8 lanes
    int l    = lane & 7;      // dim slice [l*8, l*8+8)

    float pred[2];
    if (smp < BATCH) {
        int u = users[smp];
        uint4 uv = acc16[(size_t)u * 8 + l];
        float uvals[8] = {bflo(uv.x), bfhi(uv.x), bflo(uv.y), bfhi(uv.y),
                          bflo(uv.z), bfhi(uv.z), bflo(uv.w), bfhi(uv.w)};
        #pragma unroll
        for (int j = 0; j < 2; ++j) {
            int bd = bundles[2 * smp + j];
            int s  = offB[bd];
            int d  = degB[bd];
            float part[8] = {0.f, 0.f, 0.f, 0.f, 0.f, 0.f, 0.f, 0.f};
            for (int k = sub; k < d; k += 8) {
                int c = (int)cvB[s + k];
                uint4 x = acc16[(size_t)(NU_ + c) * 8 + l];
                fma8(part, 1.f, x);
            }
            #pragma unroll
            for (int m = 8; m <= 32; m <<= 1) {
                #pragma unroll
                for (int i = 0; i < 8; ++i)
                    part[i] += __shfl_xor(part[i], m, 64);
            }
            float dp = 0.f;
            #pragma unroll
            for (int i = 0; i < 8; ++i) dp = fmaf(part[i], uvals[i], dp);
            #pragma unroll
            for (int m = 1; m <= 4; m <<= 1)
                dp += __shfl_xor(dp, m, 64);
            pred[j] = dp * (1.0f / 9.0f) / ((float)d + 1e-8f);
        }
        if (lane == 0) {
            float x = pred[0] - pred[1];
            float lv = fmaxf(-x, 0.0f) + log1pf(expf(-fabsf(x)));
            atomicAdd(loss_sum, lv);
        }
    }
    __syncthreads();
    if (threadIdx.x == 0) {
        __threadfence();
        int old = atomicAdd(done, 1);
        if (old == (int)gridDim.x - 1) {
            float total = atomicAdd(loss_sum, 0.0f);   // coherent read
            out[0] = total * (1.0f / BATCH);
            out[1] = 0.0f;
        }
    }
}

// ---------------------------------------------------------------------------
extern "C" void kernel_launch(void* const* d_in, const int* in_sizes, int n_in,
                              void* d_out, int out_size, void* d_ws, size_t ws_size,
                              hipStream_t stream) {
    const float* uf        = (const float*)d_in[0];
    const float* itf       = (const float*)d_in[1];
    const int*   prop_rows = (const int*)  d_in[4];
    const int*   prop_cols = (const int*)  d_in[5];
    const int*   bi_rows   = (const int*)  d_in[6];
    const int*   bi_cols   = (const int*)  d_in[7];
    const int*   users     = (const int*)  d_in[8];
    const int*   bundles   = (const int*)  d_in[9];
    float* out = (float*)d_out;

    char* ws = (char*)d_ws;
    uint4*        acc16    = (uint4*)       (ws + 0);            // 19.2 MB
    uint4*        f1s16    = (uint4*)       (ws + 19200000);     // 19.2 MB
    uint4*        feats16  = (uint4*)       (ws + 38400000);     // 19.2 MB
    unsigned int* binnedP  = (unsigned int*)(ws + 57600000);     // 586*20480*4 = 48.0 MB
    unsigned int* binnedB  = (unsigned int*)(ws + 105605120);    // 79*15360*4 = 4.85 MB
    int*          cellcntP = (int*)         (ws + 110458880);    // 586*512*4 = 1.2 MB
    int*          cellcntB = (int*)         (ws + 111659008);    // 79*96*4 = 30 KB
    int*          degP     = (int*)         (ws + 111689344);
    int*          offP     = (int*)         (ws + 112289344);
    float*        invsP    = (float*)       (ws + 112889344);
    int*          degB     = (int*)         (ws + 113489344);
    int*          offB     = (int*)         (ws + 113569344);
    float*        loss     = (float*)       (ws + 113649344);
    int*          done     = (int*)         (ws + 113649348);

    hipMemsetAsync(loss, 0, 8, stream);   // loss + done

    // 1) fused multisplit (private cells, no atomics) + bf16 cast
    mscast_kernel<<<MS_TOTAL + CAST_BLOCKS, 256, 0, stream>>>(
        prop_rows, prop_cols, bi_rows, bi_cols,
        binnedP, cellcntP, binnedB, cellcntB,
        (const float4*)uf, (const float4*)itf, (uint2*)feats16);

    // 2) per-bin CSR build, 512-thread blocks, two-sweep direct placement
    bin_csr_kernel<<<NBIN_P + NBIN_B, 512, 0, stream>>>(
        binnedP, cellcntP, offP, degP, invsP,
        binnedB, cellcntB, offB, degB);

    // 3-4) propagation
    layer1_kernel<<<(NTOT + 31) / 32, 256, 0, stream>>>(offP, degP, binnedP, invsP,
                                                        feats16, f1s16, acc16);
    layer2_kernel<<<(NTOT + 31) / 32, 256, 0, stream>>>(offP, degP, binnedP, invsP,
                                                        f1s16, acc16);

    // 5) fused bundle-SpMM + loss + finalize
    score_kernel<<<SCORE_BLOCKS, 256, 0, stream>>>(
        offB, degB, binnedB, acc16, users, bundles, loss, done, out);
}